// Round 1
// baseline (6701.524 us; speedup 1.0000x reference)
//
#include <hip/hip_runtime.h>
#include <math.h>

// Problem constants (B=4, T=1024, C=2048, H=16, D=128)
#define T_SEQ 1024
#define C_DIM 2048
#define H_NUM 16
#define D_HEAD 128
#define BT 4096              // B*T rows
#define QKV_N 6144           // 3*C

// ---------------------------------------------------------------------------
// Simple fp32 tiled GEMM with bias: C[M,N] = A[M,K] @ B[K,N] + bias[N]
// 64x64 tile, 256 threads, 4x4 accum per thread, K-tile = 16.
// All dims are multiples of the tile sizes for this problem -> no bounds checks.
// ---------------------------------------------------------------------------
__global__ __launch_bounds__(256) void gemm_bias(
    const float* __restrict__ A, const float* __restrict__ B,
    const float* __restrict__ bias, float* __restrict__ Cout,
    int M, int N, int K)
{
    __shared__ float As[16][65];   // [k][m], +1 pad
    __shared__ float Bs[16][68];   // [k][n], +4 pad (keeps float4 alignment)

    const int tid = threadIdx.x;
    const int m0 = blockIdx.y * 64;
    const int n0 = blockIdx.x * 64;
    const int tm = (tid >> 4) * 4;       // 0..60
    const int tn = (tid & 15) * 4;       // 0..60

    // A-tile load mapping: one float4 per thread
    const int am = tid >> 2;             // 0..63  (row within tile)
    const int ak = (tid & 3) * 4;        // 0,4,8,12
    // B-tile load mapping: one float4 per thread
    const int bk = tid >> 4;             // 0..15
    const int bn = (tid & 15) * 4;       // 0..60

    float acc[4][4] = {};

    for (int k0 = 0; k0 < K; k0 += 16) {
        float4 av = *(const float4*)&A[(size_t)(m0 + am) * K + k0 + ak];
        float4 bv = *(const float4*)&B[(size_t)(k0 + bk) * N + n0 + bn];
        As[ak + 0][am] = av.x;
        As[ak + 1][am] = av.y;
        As[ak + 2][am] = av.z;
        As[ak + 3][am] = av.w;
        *(float4*)&Bs[bk][bn] = bv;
        __syncthreads();

#pragma unroll
        for (int kk = 0; kk < 16; ++kk) {
            float a0 = As[kk][tm + 0], a1 = As[kk][tm + 1];
            float a2 = As[kk][tm + 2], a3 = As[kk][tm + 3];
            float b0 = Bs[kk][tn + 0], b1 = Bs[kk][tn + 1];
            float b2 = Bs[kk][tn + 2], b3 = Bs[kk][tn + 3];
            acc[0][0] += a0 * b0; acc[0][1] += a0 * b1; acc[0][2] += a0 * b2; acc[0][3] += a0 * b3;
            acc[1][0] += a1 * b0; acc[1][1] += a1 * b1; acc[1][2] += a1 * b2; acc[1][3] += a1 * b3;
            acc[2][0] += a2 * b0; acc[2][1] += a2 * b1; acc[2][2] += a2 * b2; acc[2][3] += a2 * b3;
            acc[3][0] += a3 * b0; acc[3][1] += a3 * b1; acc[3][2] += a3 * b2; acc[3][3] += a3 * b3;
        }
        __syncthreads();
    }

#pragma unroll
    for (int i = 0; i < 4; ++i) {
#pragma unroll
        for (int j = 0; j < 4; ++j) {
            Cout[(size_t)(m0 + tm + i) * N + n0 + tn + j] =
                acc[i][j] + bias[n0 + tn + j];
        }
    }
}

// ---------------------------------------------------------------------------
// In-place RoPE on q and k slices of qkv [B,T,3,H,D].
// One thread per (b,t,h,d2) with d2 in [0,64); handles the (d2, d2+64) pair
// for both q and k.
// ---------------------------------------------------------------------------
__global__ __launch_bounds__(256) void rope_kernel(float* __restrict__ qkv)
{
    const int idx = blockIdx.x * 256 + threadIdx.x;  // < 4*1024*16*64 = 2^22
    const int d2 = idx & 63;
    const int h  = (idx >> 6) & 15;
    const int t  = (idx >> 10) & 1023;
    const int b  = idx >> 20;

    // inv_freq = 10000^(-(2*d2)/128); ln(10000) = 9.210340371976184
    const float inv_freq = expf(-(float)(2 * d2) * (9.210340371976184f / 128.0f));
    const float fr = (float)t * inv_freq;
    const float c  = cosf(fr);
    const float sn = sinf(fr);

    const size_t row = ((size_t)(b * T_SEQ) + t) * QKV_N + h * D_HEAD + d2;

    float q1 = qkv[row], q2 = qkv[row + 64];
    qkv[row]      = q1 * c - q2 * sn;
    qkv[row + 64] = q1 * sn + q2 * c;

    float k1 = qkv[row + C_DIM], k2 = qkv[row + C_DIM + 64];
    qkv[row + C_DIM]      = k1 * c - k2 * sn;
    qkv[row + C_DIM + 64] = k1 * sn + k2 * c;
}

// ---------------------------------------------------------------------------
// Causal attention, one block (256 threads) per (b,h,t) query row.
// Reads q,k,v directly from the qkv buffer [B,T,3C] (post-RoPE).
// Scores for all keys kept in LDS (T=1024 -> 4KB), block softmax, then
// coalesced PV accumulation over D=128.
// Writes y as [B,T,C] so the proj GEMM reads row-major.
// ---------------------------------------------------------------------------
__global__ __launch_bounds__(256) void attn_kernel(
    const float* __restrict__ qkv, float* __restrict__ y)
{
    const int tid = threadIdx.x;
    const int t  = blockIdx.x & (T_SEQ - 1);
    const int bh = blockIdx.x >> 10;     // 0..63
    const int h  = bh & 15;
    const int b  = bh >> 4;

    const int rowStride = QKV_N;
    const float* base = qkv + (size_t)(b * T_SEQ) * rowStride;
    const float* qrow = base + (size_t)t * rowStride + h * D_HEAD;

    __shared__ float qs[D_HEAD];
    __shared__ float s[T_SEQ];
    __shared__ float red[4];
    __shared__ float partial[256];

    const float scale = 0.08838834764831845f;  // 1/sqrt(128)
    if (tid < D_HEAD) qs[tid] = qrow[tid] * scale;
    __syncthreads();

    const int nk = t + 1;

    // Phase A: scores s[j] = (q . k_j) * scale for j <= t
    for (int j = tid; j < nk; j += 256) {
        const float* krow = base + (size_t)j * rowStride + C_DIM + h * D_HEAD;
        float acc = 0.f;
#pragma unroll
        for (int d = 0; d < D_HEAD; d += 4) {
            float4 kv = *(const float4*)&krow[d];
            acc += qs[d] * kv.x + qs[d + 1] * kv.y + qs[d + 2] * kv.z + qs[d + 3] * kv.w;
        }
        s[j] = acc;
    }
    __syncthreads();

    const int lane = tid & 63, wid = tid >> 6;

    // max reduce
    float m = -1e30f;
    for (int j = tid; j < nk; j += 256) m = fmaxf(m, s[j]);
    for (int off = 32; off > 0; off >>= 1) m = fmaxf(m, __shfl_down(m, off, 64));
    if (lane == 0) red[wid] = m;
    __syncthreads();
    m = fmaxf(fmaxf(red[0], red[1]), fmaxf(red[2], red[3]));
    __syncthreads();  // before red is reused

    // exp + sum reduce
    float lsum = 0.f;
    for (int j = tid; j < nk; j += 256) {
        float e = __expf(s[j] - m);
        s[j] = e;
        lsum += e;
    }
    for (int off = 32; off > 0; off >>= 1) lsum += __shfl_down(lsum, off, 64);
    if (lane == 0) red[wid] = lsum;
    __syncthreads();
    const float inv = 1.f / (red[0] + red[1] + red[2] + red[3]);

    // Phase B: out[d] = sum_j p[j] * v[j][d]; split j range across two halves.
    const int d = tid & 127;
    const int half = tid >> 7;
    const float* vbase = base + 2 * C_DIM + h * D_HEAD + d;
    float acc = 0.f;
    for (int j = half; j < nk; j += 2)
        acc += s[j] * vbase[(size_t)j * rowStride];
    partial[tid] = acc;
    __syncthreads();

    if (tid < D_HEAD) {
        float r = (partial[tid] + partial[tid + 128]) * inv;
        y[((size_t)(b * T_SEQ) + t) * C_DIM + h * D_HEAD + d] = r;
    }
}

// ---------------------------------------------------------------------------
extern "C" void kernel_launch(void* const* d_in, const int* in_sizes, int n_in,
                              void* d_out, int out_size, void* d_ws, size_t ws_size,
                              hipStream_t stream) {
    const float* x      = (const float*)d_in[0];
    const float* w_attn = (const float*)d_in[1];
    const float* b_attn = (const float*)d_in[2];
    const float* w_proj = (const float*)d_in[3];
    const float* b_proj = (const float*)d_in[4];
    float* out = (float*)d_out;

    float* qkv = (float*)d_ws;                       // BT x 3C  (96 MiB)
    float* y   = qkv + (size_t)BT * QKV_N;           // BT x C   (32 MiB)

    // 1) qkv = x @ w_attn + b_attn
    gemm_bias<<<dim3(QKV_N / 64, BT / 64), 256, 0, stream>>>(
        x, w_attn, b_attn, qkv, BT, QKV_N, C_DIM);

    // 2) RoPE in place on q,k
    rope_kernel<<<(4 * T_SEQ * H_NUM * 64) / 256, 256, 0, stream>>>(qkv);

    // 3) causal attention -> y [B,T,C]
    attn_kernel<<<4 * H_NUM * T_SEQ, 256, 0, stream>>>(qkv, y);

    // 4) out = y @ w_proj + b_proj
    gemm_bias<<<dim3(C_DIM / 64, BT / 64), 256, 0, stream>>>(
        y, w_proj, b_proj, out, BT, C_DIM, C_DIM);
}

// Round 2
// 1159.300 us; speedup vs baseline: 5.7807x; 5.7807x over previous
//
#include <hip/hip_runtime.h>
#include <math.h>

#define T_SEQ 1024
#define C_DIM 2048
#define H_NUM 16
#define D_HEAD 128
#define BT 4096              // B*T rows
#define QKV_N 6144           // 3*C

typedef __bf16 bf16x8 __attribute__((ext_vector_type(8)));
typedef float f32x4 __attribute__((ext_vector_type(4)));
typedef unsigned short u16;
typedef unsigned int u32;

__device__ __forceinline__ u16 f2bf(float f) {
    u32 u = __builtin_bit_cast(u32, f);
    u += 0x7fffu + ((u >> 16) & 1u);          // RNE
    return (u16)(u >> 16);
}
__device__ __forceinline__ float bf2f(u16 s) {
    return __builtin_bit_cast(float, (u32)s << 16);
}
__device__ __forceinline__ void unpack8(uint4 u, float* f) {
    const u32 w0 = u.x, w1 = u.y, w2 = u.z, w3 = u.w;
    f[0] = __builtin_bit_cast(float, w0 << 16);
    f[1] = __builtin_bit_cast(float, w0 & 0xffff0000u);
    f[2] = __builtin_bit_cast(float, w1 << 16);
    f[3] = __builtin_bit_cast(float, w1 & 0xffff0000u);
    f[4] = __builtin_bit_cast(float, w2 << 16);
    f[5] = __builtin_bit_cast(float, w2 & 0xffff0000u);
    f[6] = __builtin_bit_cast(float, w3 << 16);
    f[7] = __builtin_bit_cast(float, w3 & 0xffff0000u);
}

// ---------------------------------------------------------------------------
// Elementwise fp32 -> bf16 cast (x -> xb). One float4 per thread.
// ---------------------------------------------------------------------------
__global__ __launch_bounds__(256) void cast_bf16(
    const float* __restrict__ in, u16* __restrict__ out)
{
    int i = blockIdx.x * 256 + threadIdx.x;
    float4 v = ((const float4*)in)[i];
    ushort4 o;
    o.x = f2bf(v.x); o.y = f2bf(v.y); o.z = f2bf(v.z); o.w = f2bf(v.w);
    ((ushort4*)out)[i] = o;
}

// ---------------------------------------------------------------------------
// fp32 [R][Cc] -> bf16 [Cc][R] transpose+cast. 32x32 tile, 256 threads.
// ---------------------------------------------------------------------------
__global__ __launch_bounds__(256) void transpose_cast(
    const float* __restrict__ in, u16* __restrict__ out, int R, int Cc)
{
    __shared__ float tile[32][33];
    const int c0 = blockIdx.x * 32, r0 = blockIdx.y * 32;
    const int tx = threadIdx.x & 31, ty = threadIdx.x >> 5;  // ty 0..7
#pragma unroll
    for (int i = 0; i < 32; i += 8)
        tile[ty + i][tx] = in[(size_t)(r0 + ty + i) * Cc + c0 + tx];
    __syncthreads();
#pragma unroll
    for (int i = 0; i < 32; i += 8)
        out[(size_t)(c0 + ty + i) * R + r0 + tx] = f2bf(tile[tx][ty + i]);
}

// ---------------------------------------------------------------------------
// bf16 MFMA GEMM (m97 structure): C[M,N] = A[M,K] @ Bt[N,K]^T + bias.
// 128x128 tile, BK=32, 256 threads = 4 waves (2x2), each wave 64x64 via
// 4x4 mfma_f32_16x16x32_bf16. LDS chunk-major [kq][row][16B], staged with
// global_load_lds width=16 (wave-uniform LDS base + lane*16).
// ---------------------------------------------------------------------------
template <int OUT_BF16>
__global__ __launch_bounds__(256) void gemm_bf16_mfma(
    const u16* __restrict__ A,    // [M][K] bf16
    const u16* __restrict__ Bt,   // [N][K] bf16 (B transposed)
    const float* __restrict__ bias,
    void* __restrict__ Cout,      // bf16 [M][N] or fp32 [M][N]
    int M, int N, int K)
{
    __shared__ alignas(16) char As[8192];   // [kq(4)][m(128)][16B]
    __shared__ alignas(16) char Bs[8192];   // [kq(4)][n(128)][16B]

    const int tid  = threadIdx.x;
    const int lane = tid & 63;
    const int w    = tid >> 6;         // wave 0..3
    const int wr   = w >> 1, wc = w & 1;
    const int m0   = blockIdx.y * 128;
    const int n0   = blockIdx.x * 128;
    const int l15  = lane & 15;
    const int kq   = lane >> 4;        // 0..3

    f32x4 acc[4][4] = {};

    // per-lane global row bases for staging (wave w stages k-chunk w*8)
    const size_t arow0 = (size_t)(m0 + lane) * K;
    const size_t arow1 = (size_t)(m0 + 64 + lane) * K;
    const size_t brow0 = (size_t)(n0 + lane) * K;
    const size_t brow1 = (size_t)(n0 + 64 + lane) * K;
    const int kcol = w * 8;

    for (int k0 = 0; k0 < K; k0 += 32) {
        __syncthreads();   // previous tile's compute done before overwrite
        __builtin_amdgcn_global_load_lds(
            (const __attribute__((address_space(1))) void*)(A + arow0 + k0 + kcol),
            (__attribute__((address_space(3))) void*)(As + w * 2048), 16, 0, 0);
        __builtin_amdgcn_global_load_lds(
            (const __attribute__((address_space(1))) void*)(A + arow1 + k0 + kcol),
            (__attribute__((address_space(3))) void*)(As + w * 2048 + 1024), 16, 0, 0);
        __builtin_amdgcn_global_load_lds(
            (const __attribute__((address_space(1))) void*)(Bt + brow0 + k0 + kcol),
            (__attribute__((address_space(3))) void*)(Bs + w * 2048), 16, 0, 0);
        __builtin_amdgcn_global_load_lds(
            (const __attribute__((address_space(1))) void*)(Bt + brow1 + k0 + kcol),
            (__attribute__((address_space(3))) void*)(Bs + w * 2048 + 1024), 16, 0, 0);
        __syncthreads();   // vmcnt(0) drain -> staged data visible

        bf16x8 af[4], bfr[4];
#pragma unroll
        for (int mt = 0; mt < 4; ++mt) {
            uint4 r = *(const uint4*)(As + kq * 2048 + (wr * 64 + mt * 16 + l15) * 16);
            af[mt] = __builtin_bit_cast(bf16x8, r);
        }
#pragma unroll
        for (int nt = 0; nt < 4; ++nt) {
            uint4 r = *(const uint4*)(Bs + kq * 2048 + (wc * 64 + nt * 16 + l15) * 16);
            bfr[nt] = __builtin_bit_cast(bf16x8, r);
        }
#pragma unroll
        for (int mt = 0; mt < 4; ++mt)
#pragma unroll
            for (int nt = 0; nt < 4; ++nt)
                acc[mt][nt] = __builtin_amdgcn_mfma_f32_16x16x32_bf16(
                    af[mt], bfr[nt], acc[mt][nt], 0, 0, 0);
    }

    // epilogue: C/D layout row=(lane>>4)*4+reg, col=lane&15
#pragma unroll
    for (int nt = 0; nt < 4; ++nt) {
        const int colg = n0 + wc * 64 + nt * 16 + l15;
        const float bv = bias[colg];
#pragma unroll
        for (int mt = 0; mt < 4; ++mt) {
#pragma unroll
            for (int r = 0; r < 4; ++r) {
                const int rowg = m0 + wr * 64 + mt * 16 + kq * 4 + r;
                const float v = acc[mt][nt][r] + bv;
                if (OUT_BF16)
                    ((u16*)Cout)[(size_t)rowg * N + colg] = f2bf(v);
                else
                    ((float*)Cout)[(size_t)rowg * N + colg] = v;
            }
        }
    }
}

// ---------------------------------------------------------------------------
// In-place RoPE on bf16 qkv [B,T,3,H,D]. Thread = (b,t,h,d4), 4 pairs each.
// ---------------------------------------------------------------------------
__global__ __launch_bounds__(256) void rope_bf16(u16* __restrict__ qkv)
{
    const int idx = blockIdx.x * 256 + threadIdx.x;   // < 2^20
    const int d4 = idx & 15;
    const int h  = (idx >> 4) & 15;
    const int t  = (idx >> 8) & 1023;
    const int b  = idx >> 18;

    const size_t row = ((size_t)(b * T_SEQ + t)) * QKV_N + h * D_HEAD;
    u16* q1p = qkv + row + d4 * 4;
    u16* q2p = q1p + 64;
    u16* k1p = q1p + C_DIM;
    u16* k2p = k1p + 64;

    ushort4 q1 = *(ushort4*)q1p, q2 = *(ushort4*)q2p;
    ushort4 k1 = *(ushort4*)k1p, k2 = *(ushort4*)k2p;
    float fq1[4] = {bf2f(q1.x), bf2f(q1.y), bf2f(q1.z), bf2f(q1.w)};
    float fq2[4] = {bf2f(q2.x), bf2f(q2.y), bf2f(q2.z), bf2f(q2.w)};
    float fk1[4] = {bf2f(k1.x), bf2f(k1.y), bf2f(k1.z), bf2f(k1.w)};
    float fk2[4] = {bf2f(k2.x), bf2f(k2.y), bf2f(k2.z), bf2f(k2.w)};
    u16 oq1[4], oq2[4], ok1[4], ok2[4];
#pragma unroll
    for (int i = 0; i < 4; ++i) {
        const int d2 = d4 * 4 + i;
        // inv_freq = 10000^(-d2/64)
        const float invf = expf(-(float)d2 * (9.210340371976184f / 64.0f));
        const float fr = (float)t * invf;
        const float c = cosf(fr), s = sinf(fr);
        oq1[i] = f2bf(fq1[i] * c - fq2[i] * s);
        oq2[i] = f2bf(fq1[i] * s + fq2[i] * c);
        ok1[i] = f2bf(fk1[i] * c - fk2[i] * s);
        ok2[i] = f2bf(fk1[i] * s + fk2[i] * c);
    }
    *(ushort4*)q1p = make_ushort4(oq1[0], oq1[1], oq1[2], oq1[3]);
    *(ushort4*)q2p = make_ushort4(oq2[0], oq2[1], oq2[2], oq2[3]);
    *(ushort4*)k1p = make_ushort4(ok1[0], ok1[1], ok1[2], ok1[3]);
    *(ushort4*)k2p = make_ushort4(ok2[0], ok2[1], ok2[2], ok2[3]);
}

// ---------------------------------------------------------------------------
// Flash attention, fp32 compute, bf16 I/O. Block = (qtile of 32, bh).
// K/V tiles of 32 staged coalesced into LDS; 2x2 score blocking; online
// softmax; 2x(2x float4) PV blocking. Writes y as bf16 [B,T,C].
// ---------------------------------------------------------------------------
__global__ __launch_bounds__(256) void attn_flash(
    const u16* __restrict__ qkv, u16* __restrict__ y)
{
    __shared__ float Qs[32][132];
    __shared__ float Ks[32][132];
    __shared__ float Vs[32][128];
    __shared__ float Ps[32][33];
    __shared__ float mrow[32], lrow[32], arow[32];

    const int tid = threadIdx.x;
    const int qt  = blockIdx.x;        // 0..31
    const int bh  = blockIdx.y;        // 0..63
    const int h   = bh & 15;
    const int b   = bh >> 4;
    const int qt0 = qt * 32;

    const size_t baserow = (size_t)(b * T_SEQ) * QKV_N + h * D_HEAD;
    const float scale = 0.08838834764831845f;   // 1/sqrt(128)

    // stage Q (scaled): 512 chunks of 8 elements, 2 per thread
    {
        const int c0 = tid & 15, r0 = tid >> 4;
#pragma unroll
        for (int rr = 0; rr < 32; rr += 16) {
            const int r = r0 + rr;
            uint4 u = *(const uint4*)(qkv + baserow + (size_t)(qt0 + r) * QKV_N + c0 * 8);
            float f[8]; unpack8(u, f);
#pragma unroll
            for (int i = 0; i < 8; ++i) Qs[r][c0 * 8 + i] = f[i] * scale;
        }
    }
    if (tid < 32) { mrow[tid] = -1e30f; lrow[tid] = 0.f; }

    const int qi = tid >> 4;           // 0..15 -> rows {qi, qi+16}
    const int ki = tid & 15;           // cols {ki, ki+16}
    const int cc = (tid & 15) * 4;     // PV cols {cc..cc+3, cc+64..cc+67}
    f32x4 o00 = {}, o01 = {}, o10 = {}, o11 = {};

    const int ntiles = qt + 1;
    for (int kt = 0; kt < ntiles; ++kt) {
        const int kt0 = kt * 32;
        __syncthreads();               // everyone done with prev Ks/Vs/Ps
        {
            const int c0 = tid & 15, r0 = tid >> 4;
#pragma unroll
            for (int rr = 0; rr < 32; rr += 16) {
                const int r = r0 + rr;
                const size_t grow = baserow + (size_t)(kt0 + r) * QKV_N;
                uint4 uk = *(const uint4*)(qkv + grow + C_DIM + c0 * 8);
                uint4 uv = *(const uint4*)(qkv + grow + 2 * C_DIM + c0 * 8);
                float fk[8], fv[8]; unpack8(uk, fk); unpack8(uv, fv);
#pragma unroll
                for (int i = 0; i < 8; ++i) {
                    Ks[r][c0 * 8 + i] = fk[i];
                    Vs[r][c0 * 8 + i] = fv[i];
                }
            }
        }
        __syncthreads();

        // scores: 2x2 per thread
        float s00 = 0.f, s01 = 0.f, s10 = 0.f, s11 = 0.f;
#pragma unroll 4
        for (int d = 0; d < 128; d += 4) {
            float4 qa = *(const float4*)&Qs[qi][d];
            float4 qb = *(const float4*)&Qs[qi + 16][d];
            float4 ka = *(const float4*)&Ks[ki][d];
            float4 kb = *(const float4*)&Ks[ki + 16][d];
            s00 += qa.x * ka.x + qa.y * ka.y + qa.z * ka.z + qa.w * ka.w;
            s01 += qa.x * kb.x + qa.y * kb.y + qa.z * kb.z + qa.w * kb.w;
            s10 += qb.x * ka.x + qb.y * ka.y + qb.z * ka.z + qb.w * ka.w;
            s11 += qb.x * kb.x + qb.y * kb.y + qb.z * kb.z + qb.w * kb.w;
        }
        if (kt == qt) {                // diagonal tile: mask col > row
            if (ki > qi)       s00 = -1e30f;
            if (ki + 16 > qi)  s01 = -1e30f;
            if (ki > qi + 16)  s10 = -1e30f;
            if (ki > qi)       s11 = -1e30f;   // (ki+16 > qi+16)
        }
        Ps[qi][ki] = s00; Ps[qi][ki + 16] = s01;
        Ps[qi + 16][ki] = s10; Ps[qi + 16][ki + 16] = s11;
        __syncthreads();

        // online softmax update, one thread per q-row
        if (tid < 32) {
            const float mo = mrow[tid];
            float mx = mo;
            for (int j = 0; j < 32; ++j) mx = fmaxf(mx, Ps[tid][j]);
            const float al = __expf(mo - mx);
            float sum = 0.f;
            for (int j = 0; j < 32; ++j) {
                const float e = __expf(Ps[tid][j] - mx);
                Ps[tid][j] = e;
                sum += e;
            }
            lrow[tid] = lrow[tid] * al + sum;
            mrow[tid] = mx;
            arow[tid] = al;
        }
        __syncthreads();

        // PV: rescale + accumulate
        const float a0 = arow[qi], a1 = arow[qi + 16];
        o00 *= a0; o01 *= a0; o10 *= a1; o11 *= a1;
#pragma unroll 4
        for (int j = 0; j < 32; ++j) {
            const float p0 = Ps[qi][j], p1 = Ps[qi + 16][j];
            f32x4 v0 = *(const f32x4*)&Vs[j][cc];
            f32x4 v1 = *(const f32x4*)&Vs[j][cc + 64];
            o00 += v0 * p0; o01 += v1 * p0;
            o10 += v0 * p1; o11 += v1 * p1;
        }
    }

    // write out (bf16), divide by l
    const float i0 = 1.f / lrow[qi], i1 = 1.f / lrow[qi + 16];
    const size_t out0 = (size_t)(b * T_SEQ + qt0 + qi) * C_DIM + h * D_HEAD;
    const size_t out1 = (size_t)(b * T_SEQ + qt0 + qi + 16) * C_DIM + h * D_HEAD;
    *(ushort4*)(y + out0 + cc) =
        make_ushort4(f2bf(o00[0] * i0), f2bf(o00[1] * i0), f2bf(o00[2] * i0), f2bf(o00[3] * i0));
    *(ushort4*)(y + out0 + cc + 64) =
        make_ushort4(f2bf(o01[0] * i0), f2bf(o01[1] * i0), f2bf(o01[2] * i0), f2bf(o01[3] * i0));
    *(ushort4*)(y + out1 + cc) =
        make_ushort4(f2bf(o10[0] * i1), f2bf(o10[1] * i1), f2bf(o10[2] * i1), f2bf(o10[3] * i1));
    *(ushort4*)(y + out1 + cc + 64) =
        make_ushort4(f2bf(o11[0] * i1), f2bf(o11[1] * i1), f2bf(o11[2] * i1), f2bf(o11[3] * i1));
}

// ---------------------------------------------------------------------------
extern "C" void kernel_launch(void* const* d_in, const int* in_sizes, int n_in,
                              void* d_out, int out_size, void* d_ws, size_t ws_size,
                              hipStream_t stream) {
    const float* x      = (const float*)d_in[0];
    const float* w_attn = (const float*)d_in[1];
    const float* b_attn = (const float*)d_in[2];
    const float* w_proj = (const float*)d_in[3];
    const float* b_proj = (const float*)d_in[4];
    float* out = (float*)d_out;

    char* ws = (char*)d_ws;
    u16* xb   = (u16*)(ws);                                   // 16.8 MB
    u16* waT  = (u16*)(ws + 16777216);                        // 25.2 MB  [6144][2048]
    u16* wpT  = (u16*)(ws + 41943040);                        // 8.4 MB   [2048][2048]
    u16* qkvb = (u16*)(ws + 50331648);                        // 50.3 MB  [4096][6144]
    u16* yb   = (u16*)(ws + 100663296);                       // 16.8 MB  [4096][2048]

    // 1) casts / weight transposes
    cast_bf16<<<(BT * C_DIM / 4) / 256, 256, 0, stream>>>(x, xb);
    transpose_cast<<<dim3(QKV_N / 32, C_DIM / 32), 256, 0, stream>>>(w_attn, waT, C_DIM, QKV_N);
    transpose_cast<<<dim3(C_DIM / 32, C_DIM / 32), 256, 0, stream>>>(w_proj, wpT, C_DIM, C_DIM);

    // 2) qkv = x @ w_attn + b_attn  (bf16 out)
    gemm_bf16_mfma<1><<<dim3(QKV_N / 128, BT / 128), 256, 0, stream>>>(
        xb, waT, b_attn, qkvb, BT, QKV_N, C_DIM);

    // 3) RoPE in place on q,k
    rope_bf16<<<(4 * T_SEQ * H_NUM * 16) / 256, 256, 0, stream>>>(qkvb);

    // 4) flash attention -> yb [B,T,C] bf16
    attn_flash<<<dim3(T_SEQ / 32, 4 * H_NUM), 256, 0, stream>>>(qkvb, yb);

    // 5) out = y @ w_proj + b_proj  (fp32 out)
    gemm_bf16_mfma<0><<<dim3(C_DIM / 128, BT / 128), 256, 0, stream>>>(
        yb, wpT, b_proj, out, BT, C_DIM, C_DIM);
}

// Round 3
// 550.922 us; speedup vs baseline: 12.1642x; 2.1043x over previous
//
#include <hip/hip_runtime.h>
#include <math.h>

#define T_SEQ 1024
#define C_DIM 2048
#define H_NUM 16
#define D_HEAD 128
#define BT 4096              // B*T rows
#define QKV_N 6144           // 3*C

typedef __bf16 bf16x8 __attribute__((ext_vector_type(8)));
typedef float f32x4 __attribute__((ext_vector_type(4)));
typedef unsigned short u16;
typedef unsigned int u32;

#define AS1C(p) ((const __attribute__((address_space(1))) void*)(p))
#define AS3(p)  ((__attribute__((address_space(3))) void*)(p))

__device__ __forceinline__ u16 f2bf(float f) {
    u32 u = __builtin_bit_cast(u32, f);
    u += 0x7fffu + ((u >> 16) & 1u);          // RNE
    return (u16)(u >> 16);
}
__device__ __forceinline__ float bf2f(u16 s) {
    return __builtin_bit_cast(float, (u32)s << 16);
}

// ---------------------------------------------------------------------------
// Elementwise fp32 -> bf16 cast (x -> xb).
// ---------------------------------------------------------------------------
__global__ __launch_bounds__(256) void cast_bf16(
    const float* __restrict__ in, u16* __restrict__ out)
{
    int i = blockIdx.x * 256 + threadIdx.x;
    float4 v = ((const float4*)in)[i];
    ushort4 o;
    o.x = f2bf(v.x); o.y = f2bf(v.y); o.z = f2bf(v.z); o.w = f2bf(v.w);
    ((ushort4*)out)[i] = o;
}

// ---------------------------------------------------------------------------
// fp32 [R][Cc] -> bf16 [Cc][R] transpose+cast. 32x32 tile, 256 threads.
// ---------------------------------------------------------------------------
__global__ __launch_bounds__(256) void transpose_cast(
    const float* __restrict__ in, u16* __restrict__ out, int R, int Cc)
{
    __shared__ float tile[32][33];
    const int c0 = blockIdx.x * 32, r0 = blockIdx.y * 32;
    const int tx = threadIdx.x & 31, ty = threadIdx.x >> 5;  // ty 0..7
#pragma unroll
    for (int i = 0; i < 32; i += 8)
        tile[ty + i][tx] = in[(size_t)(r0 + ty + i) * Cc + c0 + tx];
    __syncthreads();
#pragma unroll
    for (int i = 0; i < 32; i += 8)
        out[(size_t)(c0 + ty + i) * R + r0 + tx] = f2bf(tile[tx][ty + i]);
}

// ---------------------------------------------------------------------------
// bf16 MFMA GEMM (m97 structure): C[M,N] = A[M,K] @ Bt[N,K]^T + bias.
// ---------------------------------------------------------------------------
template <int OUT_BF16>
__global__ __launch_bounds__(256) void gemm_bf16_mfma(
    const u16* __restrict__ A,    // [M][K] bf16
    const u16* __restrict__ Bt,   // [N][K] bf16 (B transposed)
    const float* __restrict__ bias,
    void* __restrict__ Cout,      // bf16 [M][N] or fp32 [M][N]
    int M, int N, int K)
{
    __shared__ alignas(16) char As[8192];   // [kq(4)][m(128)][16B]
    __shared__ alignas(16) char Bs[8192];   // [kq(4)][n(128)][16B]

    const int tid  = threadIdx.x;
    const int lane = tid & 63;
    const int w    = tid >> 6;
    const int wr   = w >> 1, wc = w & 1;
    const int m0   = blockIdx.y * 128;
    const int n0   = blockIdx.x * 128;
    const int l15  = lane & 15;
    const int kq   = lane >> 4;

    f32x4 acc[4][4] = {};

    const size_t arow0 = (size_t)(m0 + lane) * K;
    const size_t arow1 = (size_t)(m0 + 64 + lane) * K;
    const size_t brow0 = (size_t)(n0 + lane) * K;
    const size_t brow1 = (size_t)(n0 + 64 + lane) * K;
    const int kcol = w * 8;

    for (int k0 = 0; k0 < K; k0 += 32) {
        __syncthreads();
        __builtin_amdgcn_global_load_lds(AS1C(A + arow0 + k0 + kcol),
                                         AS3(As + w * 2048), 16, 0, 0);
        __builtin_amdgcn_global_load_lds(AS1C(A + arow1 + k0 + kcol),
                                         AS3(As + w * 2048 + 1024), 16, 0, 0);
        __builtin_amdgcn_global_load_lds(AS1C(Bt + brow0 + k0 + kcol),
                                         AS3(Bs + w * 2048), 16, 0, 0);
        __builtin_amdgcn_global_load_lds(AS1C(Bt + brow1 + k0 + kcol),
                                         AS3(Bs + w * 2048 + 1024), 16, 0, 0);
        __syncthreads();

        bf16x8 af[4], bfr[4];
#pragma unroll
        for (int mt = 0; mt < 4; ++mt) {
            uint4 r = *(const uint4*)(As + kq * 2048 + (wr * 64 + mt * 16 + l15) * 16);
            af[mt] = __builtin_bit_cast(bf16x8, r);
        }
#pragma unroll
        for (int nt = 0; nt < 4; ++nt) {
            uint4 r = *(const uint4*)(Bs + kq * 2048 + (wc * 64 + nt * 16 + l15) * 16);
            bfr[nt] = __builtin_bit_cast(bf16x8, r);
        }
#pragma unroll
        for (int mt = 0; mt < 4; ++mt)
#pragma unroll
            for (int nt = 0; nt < 4; ++nt)
                acc[mt][nt] = __builtin_amdgcn_mfma_f32_16x16x32_bf16(
                    af[mt], bfr[nt], acc[mt][nt], 0, 0, 0);
    }

#pragma unroll
    for (int nt = 0; nt < 4; ++nt) {
        const int colg = n0 + wc * 64 + nt * 16 + l15;
        const float bv = bias[colg];
#pragma unroll
        for (int mt = 0; mt < 4; ++mt) {
#pragma unroll
            for (int r = 0; r < 4; ++r) {
                const int rowg = m0 + wr * 64 + mt * 16 + kq * 4 + r;
                const float v = acc[mt][nt][r] + bv;
                if (OUT_BF16)
                    ((u16*)Cout)[(size_t)rowg * N + colg] = f2bf(v);
                else
                    ((float*)Cout)[(size_t)rowg * N + colg] = v;
            }
        }
    }
}

// ---------------------------------------------------------------------------
// In-place RoPE on bf16 qkv [B,T,3,H,D].
// ---------------------------------------------------------------------------
__global__ __launch_bounds__(256) void rope_bf16(u16* __restrict__ qkv)
{
    const int idx = blockIdx.x * 256 + threadIdx.x;   // < 2^20
    const int d4 = idx & 15;
    const int h  = (idx >> 4) & 15;
    const int t  = (idx >> 8) & 1023;
    const int b  = idx >> 18;

    const size_t row = ((size_t)(b * T_SEQ + t)) * QKV_N + h * D_HEAD;
    u16* q1p = qkv + row + d4 * 4;
    u16* q2p = q1p + 64;
    u16* k1p = q1p + C_DIM;
    u16* k2p = k1p + 64;

    ushort4 q1 = *(ushort4*)q1p, q2 = *(ushort4*)q2p;
    ushort4 k1 = *(ushort4*)k1p, k2 = *(ushort4*)k2p;
    float fq1[4] = {bf2f(q1.x), bf2f(q1.y), bf2f(q1.z), bf2f(q1.w)};
    float fq2[4] = {bf2f(q2.x), bf2f(q2.y), bf2f(q2.z), bf2f(q2.w)};
    float fk1[4] = {bf2f(k1.x), bf2f(k1.y), bf2f(k1.z), bf2f(k1.w)};
    float fk2[4] = {bf2f(k2.x), bf2f(k2.y), bf2f(k2.z), bf2f(k2.w)};
    u16 oq1[4], oq2[4], ok1[4], ok2[4];
#pragma unroll
    for (int i = 0; i < 4; ++i) {
        const int d2 = d4 * 4 + i;
        const float invf = expf(-(float)d2 * (9.210340371976184f / 64.0f));
        const float fr = (float)t * invf;
        const float c = cosf(fr), s = sinf(fr);
        oq1[i] = f2bf(fq1[i] * c - fq2[i] * s);
        oq2[i] = f2bf(fq1[i] * s + fq2[i] * c);
        ok1[i] = f2bf(fk1[i] * c - fk2[i] * s);
        ok2[i] = f2bf(fk1[i] * s + fk2[i] * c);
    }
    *(ushort4*)q1p = make_ushort4(oq1[0], oq1[1], oq1[2], oq1[3]);
    *(ushort4*)q2p = make_ushort4(oq2[0], oq2[1], oq2[2], oq2[3]);
    *(ushort4*)k1p = make_ushort4(ok1[0], ok1[1], ok1[2], ok1[3]);
    *(ushort4*)k2p = make_ushort4(ok2[0], ok2[1], ok2[2], ok2[3]);
}

// ---------------------------------------------------------------------------
// K/V prep (after RoPE): Kc[b,h,t,d] contiguous copy of K; Vt[b,h,d,t]
// transposed V. One thread per t-row per (b,h); 256 blocks x 256 threads.
// ---------------------------------------------------------------------------
__global__ __launch_bounds__(256) void kv_prep(
    const u16* __restrict__ qkv, u16* __restrict__ Kc, u16* __restrict__ Vt)
{
    const int tid = threadIdx.x;
    const int blk = blockIdx.x;          // b(4) x h(16) x ttile(4)
    const int tt = blk & 3;
    const int h  = (blk >> 2) & 15;
    const int b  = blk >> 6;
    const int t  = tt * 256 + tid;
    const int bh = b * 16 + h;

    const size_t src  = ((size_t)(b * T_SEQ + t)) * QKV_N + h * D_HEAD;
    const size_t kdst = ((size_t)(bh * T_SEQ + t)) * D_HEAD;
    const size_t vdst = ((size_t)bh * D_HEAD) * T_SEQ + t;

#pragma unroll
    for (int c = 0; c < 16; ++c)
        *(uint4*)(Kc + kdst + c * 8) = *(const uint4*)(qkv + src + C_DIM + c * 8);

#pragma unroll
    for (int c = 0; c < 16; ++c) {
        uint4 v = *(const uint4*)(qkv + src + 2 * C_DIM + c * 8);
        u16 e[8];
        e[0] = (u16)(v.x & 0xffff); e[1] = (u16)(v.x >> 16);
        e[2] = (u16)(v.y & 0xffff); e[3] = (u16)(v.y >> 16);
        e[4] = (u16)(v.z & 0xffff); e[5] = (u16)(v.z >> 16);
        e[6] = (u16)(v.w & 0xffff); e[7] = (u16)(v.w >> 16);
#pragma unroll
        for (int j = 0; j < 8; ++j)
            Vt[vdst + (size_t)(c * 8 + j) * T_SEQ] = e[j];
    }
}

// ---------------------------------------------------------------------------
// MFMA flash attention. Block = (qt of 64 rows) x (b,h); 4 waves, wave w owns
// q-rows [qt*64+w*16, +16). K-tile = 64. QK^T and PV on matrix cores,
// fp32 online softmax in registers. P round-trips LDS (C-layout -> A-layout),
// per-wave private (no barrier). Writes y bf16 [B,T,C].
// ---------------------------------------------------------------------------
__global__ __launch_bounds__(256) void attn_mfma(
    const u16* __restrict__ qkv,   // post-rope, for Q
    const u16* __restrict__ Kc,    // [B,H,T,D]
    const u16* __restrict__ Vt,    // [B,H,D,T]
    u16* __restrict__ y)
{
    __shared__ alignas(16) char KsL[16384];     // [cd(16)][row(64)][16B]
    __shared__ alignas(16) char VtsL[16384];    // [jc(8)][drow(128)][16B]
    __shared__ alignas(16) char PwL[4][2176];   // per-wave [jc(8)][q(16)][16B], stride 272

    const int tid  = threadIdx.x;
    const int lane = tid & 63;
    const int w    = tid >> 6;
    const int l15  = lane & 15;
    const int l4   = lane >> 4;
    const int qt   = blockIdx.x;     // 0..15
    const int bh   = blockIdx.y;     // 0..63
    const int h    = bh & 15;
    const int b    = bh >> 4;

    // Q fragments (A-layout: m=lane&15, k=(lane>>4)*8+j), kept in regs
    const int qrow = qt * 64 + w * 16 + l15;
    const u16* qptr = qkv + ((size_t)(b * T_SEQ + qrow)) * QKV_N + h * D_HEAD;
    bf16x8 qf[4];
#pragma unroll
    for (int f = 0; f < 4; ++f)
        qf[f] = __builtin_bit_cast(bf16x8, *(const uint4*)(qptr + f * 32 + l4 * 8));

    const size_t kbase = (size_t)bh * T_SEQ * D_HEAD;
    const size_t vbase = (size_t)bh * D_HEAD * T_SEQ;
    const float scale = 0.08838834764831845f;   // 1/sqrt(128)

    f32x4 o[8] = {};                 // O[q=l4*4+r][d=db*16+l15]
    float mrow[4] = {-1e30f, -1e30f, -1e30f, -1e30f};
    float lrow[4] = {};

    char* pw = PwL[w];

    for (int kt = 0; kt <= qt; ++kt) {
        __syncthreads();             // done reading prev Ks/Vts
        // stage K-tile: wave w stages d-chunks cd = w*4..w*4+3
        {
            const u16* ksrc = Kc + kbase + (size_t)(kt * 64 + lane) * D_HEAD;
#pragma unroll
            for (int i = 0; i < 4; ++i) {
                const int cd = w * 4 + i;
                __builtin_amdgcn_global_load_lds(AS1C(ksrc + cd * 8),
                                                 AS3(KsL + cd * 1024), 16, 0, 0);
            }
        }
        // stage Vt-tile: wave w stages jc in {w, w+4}, d halves 0/1
#pragma unroll
        for (int i = 0; i < 4; ++i) {
            const int jc = w + (i >> 1) * 4;
            const int dh = i & 1;
            const u16* vsrc = Vt + vbase + (size_t)(dh * 64 + lane) * T_SEQ
                              + kt * 64 + jc * 8;
            __builtin_amdgcn_global_load_lds(AS1C(vsrc),
                                             AS3(VtsL + jc * 2048 + dh * 1024), 16, 0, 0);
        }
        __syncthreads();             // staging visible

        // scores: S[q][k] via 16 MFMAs
        f32x4 sacc[4] = {};
#pragma unroll
        for (int nb = 0; nb < 4; ++nb)
#pragma unroll
            for (int kc = 0; kc < 4; ++kc) {
                bf16x8 kf = __builtin_bit_cast(bf16x8,
                    *(const uint4*)(KsL + (kc * 4 + l4) * 1024 + (nb * 16 + l15) * 16));
                sacc[nb] = __builtin_amdgcn_mfma_f32_16x16x32_bf16(
                    qf[kc], kf, sacc[nb], 0, 0, 0);
            }

        // scale + causal mask (diagonal tile only)
#pragma unroll
        for (int nb = 0; nb < 4; ++nb)
#pragma unroll
            for (int r = 0; r < 4; ++r) {
                float s = sacc[nb][r] * scale;
                if (kt == qt && (nb * 16 + l15) > (w * 16 + l4 * 4 + r))
                    s = -1e30f;
                sacc[nb][r] = s;
            }

        // online softmax per row r (rows l4*4+r, cols across 16 lanes x 4 nb)
        float alpha[4];
#pragma unroll
        for (int r = 0; r < 4; ++r) {
            float mx = fmaxf(fmaxf(sacc[0][r], sacc[1][r]),
                             fmaxf(sacc[2][r], sacc[3][r]));
#pragma unroll
            for (int off = 1; off < 16; off <<= 1)
                mx = fmaxf(mx, __shfl_xor(mx, off, 64));
            const float mn = fmaxf(mrow[r], mx);
            alpha[r] = __expf(mrow[r] - mn);
            mrow[r] = mn;
            float ls = 0.f;
#pragma unroll
            for (int nb = 0; nb < 4; ++nb) {
                const float e = __expf(sacc[nb][r] - mn);
                sacc[nb][r] = e;
                ls += e;
            }
#pragma unroll
            for (int off = 1; off < 16; off <<= 1)
                ls += __shfl_xor(ls, off, 64);
            lrow[r] = lrow[r] * alpha[r] + ls;
        }

        // rescale O
#pragma unroll
        for (int db = 0; db < 8; ++db)
#pragma unroll
            for (int r = 0; r < 4; ++r)
                o[db][r] *= alpha[r];

        // P: C-layout regs -> bf16 -> per-wave LDS in A-layout chunks
#pragma unroll
        for (int nb = 0; nb < 4; ++nb)
#pragma unroll
            for (int r = 0; r < 4; ++r) {
                const int j = nb * 16 + l15;      // local key 0..63
                const int q = l4 * 4 + r;         // local q-row 0..15
                *(u16*)(pw + (j >> 3) * 272 + q * 16 + (j & 7) * 2) =
                    f2bf(sacc[nb][r]);
            }

        // PV: O += P @ V  (A=P from LDS, B=Vt chunks)
        bf16x8 pf[2];
#pragma unroll
        for (int kc2 = 0; kc2 < 2; ++kc2)
            pf[kc2] = __builtin_bit_cast(bf16x8,
                *(const uint4*)(pw + (kc2 * 4 + l4) * 272 + l15 * 16));
#pragma unroll
        for (int db = 0; db < 8; ++db)
#pragma unroll
            for (int kc2 = 0; kc2 < 2; ++kc2) {
                bf16x8 vf = __builtin_bit_cast(bf16x8,
                    *(const uint4*)(VtsL + (kc2 * 4 + l4) * 2048 + (db * 16 + l15) * 16));
                o[db] = __builtin_amdgcn_mfma_f32_16x16x32_bf16(
                    pf[kc2], vf, o[db], 0, 0, 0);
            }
    }

    // epilogue: normalize and write
    float inv[4];
#pragma unroll
    for (int r = 0; r < 4; ++r) inv[r] = 1.f / lrow[r];
#pragma unroll
    for (int db = 0; db < 8; ++db)
#pragma unroll
        for (int r = 0; r < 4; ++r) {
            const int q = qt * 64 + w * 16 + l4 * 4 + r;
            const int d = h * D_HEAD + db * 16 + l15;
            y[(size_t)(b * T_SEQ + q) * C_DIM + d] = f2bf(o[db][r] * inv[r]);
        }
}

// ---------------------------------------------------------------------------
extern "C" void kernel_launch(void* const* d_in, const int* in_sizes, int n_in,
                              void* d_out, int out_size, void* d_ws, size_t ws_size,
                              hipStream_t stream) {
    const float* x      = (const float*)d_in[0];
    const float* w_attn = (const float*)d_in[1];
    const float* b_attn = (const float*)d_in[2];
    const float* w_proj = (const float*)d_in[3];
    const float* b_proj = (const float*)d_in[4];
    float* out = (float*)d_out;

    char* ws = (char*)d_ws;
    // Region A (reused): xb+waT before GEMM1, Kc+Vt after.
    u16* xb   = (u16*)(ws);                        // [4096][2048]   16.78 MB
    u16* waT  = (u16*)(ws + 16777216);             // [6144][2048]   25.17 MB
    u16* Kc   = (u16*)(ws);                        // [64][1024][128] 16.78 MB
    u16* Vt   = (u16*)(ws + 16777216);             // [64][128][1024] 16.78 MB
    u16* wpT  = (u16*)(ws + 41943040);             // [2048][2048]    8.39 MB
    u16* qkvb = (u16*)(ws + 50331648);             // [4096][6144]   50.33 MB
    u16* yb   = (u16*)(ws + 100663296);            // [4096][2048]   16.78 MB

    // 1) casts / weight transposes
    cast_bf16<<<(BT * C_DIM / 4) / 256, 256, 0, stream>>>(x, xb);
    transpose_cast<<<dim3(QKV_N / 32, C_DIM / 32), 256, 0, stream>>>(w_attn, waT, C_DIM, QKV_N);
    transpose_cast<<<dim3(C_DIM / 32, C_DIM / 32), 256, 0, stream>>>(w_proj, wpT, C_DIM, C_DIM);

    // 2) qkv = x @ w_attn + b_attn  (bf16 out)
    gemm_bf16_mfma<1><<<dim3(QKV_N / 128, BT / 128), 256, 0, stream>>>(
        xb, waT, b_attn, qkvb, BT, QKV_N, C_DIM);

    // 3) RoPE in place on q,k
    rope_bf16<<<(4 * T_SEQ * H_NUM * 16) / 256, 256, 0, stream>>>(qkvb);

    // 4) K/V prep (overwrites xb/waT region — GEMM1 already consumed them)
    kv_prep<<<256, 256, 0, stream>>>(qkvb, Kc, Vt);

    // 5) MFMA flash attention -> yb [B,T,C] bf16
    attn_mfma<<<dim3(T_SEQ / 64, 4 * H_NUM), 256, 0, stream>>>(qkvb, Kc, Vt, yb);

    // 6) out = y @ w_proj + b_proj  (fp32 out)
    gemm_bf16_mfma<0><<<dim3(C_DIM / 128, BT / 128), 256, 0, stream>>>(
        yb, wpT, b_proj, out, BT, C_DIM, C_DIM);
}

// Round 4
// 514.500 us; speedup vs baseline: 13.0253x; 1.0708x over previous
//
#include <hip/hip_runtime.h>
#include <math.h>

#define T_SEQ 1024
#define C_DIM 2048
#define H_NUM 16
#define D_HEAD 128
#define BT 4096              // B*T rows
#define QKV_N 6144           // 3*C

typedef __bf16 bf16x8 __attribute__((ext_vector_type(8)));
typedef float f32x4 __attribute__((ext_vector_type(4)));
typedef unsigned short u16;
typedef unsigned int u32;

#define AS1C(p) ((const __attribute__((address_space(1))) void*)(p))
#define AS3(p)  ((__attribute__((address_space(3))) void*)(p))

__device__ __forceinline__ u16 f2bf(float f) {
    u32 u = __builtin_bit_cast(u32, f);
    u += 0x7fffu + ((u >> 16) & 1u);          // RNE
    return (u16)(u >> 16);
}
__device__ __forceinline__ void unpack8(uint4 u, float* f) {
    const u32 w0 = u.x, w1 = u.y, w2 = u.z, w3 = u.w;
    f[0] = __builtin_bit_cast(float, w0 << 16);
    f[1] = __builtin_bit_cast(float, w0 & 0xffff0000u);
    f[2] = __builtin_bit_cast(float, w1 << 16);
    f[3] = __builtin_bit_cast(float, w1 & 0xffff0000u);
    f[4] = __builtin_bit_cast(float, w2 << 16);
    f[5] = __builtin_bit_cast(float, w2 & 0xffff0000u);
    f[6] = __builtin_bit_cast(float, w3 << 16);
    f[7] = __builtin_bit_cast(float, w3 & 0xffff0000u);
}
__device__ __forceinline__ uint4 pack8(const float* f) {
    uint4 u;
    u.x = (u32)f2bf(f[0]) | ((u32)f2bf(f[1]) << 16);
    u.y = (u32)f2bf(f[2]) | ((u32)f2bf(f[3]) << 16);
    u.z = (u32)f2bf(f[4]) | ((u32)f2bf(f[5]) << 16);
    u.w = (u32)f2bf(f[6]) | ((u32)f2bf(f[7]) << 16);
    return u;
}

// ---------------------------------------------------------------------------
// Elementwise fp32 -> bf16 cast (x -> xb).
// ---------------------------------------------------------------------------
__global__ __launch_bounds__(256) void cast_bf16(
    const float* __restrict__ in, u16* __restrict__ out)
{
    int i = blockIdx.x * 256 + threadIdx.x;
    float4 v = ((const float4*)in)[i];
    ushort4 o;
    o.x = f2bf(v.x); o.y = f2bf(v.y); o.z = f2bf(v.z); o.w = f2bf(v.w);
    ((ushort4*)out)[i] = o;
}

// ---------------------------------------------------------------------------
// fp32 [R][Cc] -> bf16 [Cc][R] transpose+cast. 32x32 tile, 256 threads.
// ---------------------------------------------------------------------------
__global__ __launch_bounds__(256) void transpose_cast(
    const float* __restrict__ in, u16* __restrict__ out, int R, int Cc)
{
    __shared__ float tile[32][33];
    const int c0 = blockIdx.x * 32, r0 = blockIdx.y * 32;
    const int tx = threadIdx.x & 31, ty = threadIdx.x >> 5;  // ty 0..7
#pragma unroll
    for (int i = 0; i < 32; i += 8)
        tile[ty + i][tx] = in[(size_t)(r0 + ty + i) * Cc + c0 + tx];
    __syncthreads();
#pragma unroll
    for (int i = 0; i < 32; i += 8)
        out[(size_t)(c0 + ty + i) * R + r0 + tx] = f2bf(tile[tx][ty + i]);
}

// ---------------------------------------------------------------------------
// bf16 MFMA GEMM (m97 structure): C[M,N] = A[M,K] @ Bt[N,K]^T + bias.
// ---------------------------------------------------------------------------
template <int OUT_BF16>
__global__ __launch_bounds__(256) void gemm_bf16_mfma(
    const u16* __restrict__ A,    // [M][K] bf16
    const u16* __restrict__ Bt,   // [N][K] bf16 (B transposed)
    const float* __restrict__ bias,
    void* __restrict__ Cout,      // bf16 [M][N] or fp32 [M][N]
    int M, int N, int K)
{
    __shared__ alignas(16) char As[8192];   // [kq(4)][m(128)][16B]
    __shared__ alignas(16) char Bs[8192];   // [kq(4)][n(128)][16B]

    const int tid  = threadIdx.x;
    const int lane = tid & 63;
    const int w    = tid >> 6;
    const int wr   = w >> 1, wc = w & 1;
    const int m0   = blockIdx.y * 128;
    const int n0   = blockIdx.x * 128;
    const int l15  = lane & 15;
    const int kq   = lane >> 4;

    f32x4 acc[4][4] = {};

    const size_t arow0 = (size_t)(m0 + lane) * K;
    const size_t arow1 = (size_t)(m0 + 64 + lane) * K;
    const size_t brow0 = (size_t)(n0 + lane) * K;
    const size_t brow1 = (size_t)(n0 + 64 + lane) * K;
    const int kcol = w * 8;

    for (int k0 = 0; k0 < K; k0 += 32) {
        __syncthreads();
        __builtin_amdgcn_global_load_lds(AS1C(A + arow0 + k0 + kcol),
                                         AS3(As + w * 2048), 16, 0, 0);
        __builtin_amdgcn_global_load_lds(AS1C(A + arow1 + k0 + kcol),
                                         AS3(As + w * 2048 + 1024), 16, 0, 0);
        __builtin_amdgcn_global_load_lds(AS1C(Bt + brow0 + k0 + kcol),
                                         AS3(Bs + w * 2048), 16, 0, 0);
        __builtin_amdgcn_global_load_lds(AS1C(Bt + brow1 + k0 + kcol),
                                         AS3(Bs + w * 2048 + 1024), 16, 0, 0);
        __syncthreads();

        bf16x8 af[4], bfr[4];
#pragma unroll
        for (int mt = 0; mt < 4; ++mt) {
            uint4 r = *(const uint4*)(As + kq * 2048 + (wr * 64 + mt * 16 + l15) * 16);
            af[mt] = __builtin_bit_cast(bf16x8, r);
        }
#pragma unroll
        for (int nt = 0; nt < 4; ++nt) {
            uint4 r = *(const uint4*)(Bs + kq * 2048 + (wc * 64 + nt * 16 + l15) * 16);
            bfr[nt] = __builtin_bit_cast(bf16x8, r);
        }
#pragma unroll
        for (int mt = 0; mt < 4; ++mt)
#pragma unroll
            for (int nt = 0; nt < 4; ++nt)
                acc[mt][nt] = __builtin_amdgcn_mfma_f32_16x16x32_bf16(
                    af[mt], bfr[nt], acc[mt][nt], 0, 0, 0);
    }

#pragma unroll
    for (int nt = 0; nt < 4; ++nt) {
        const int colg = n0 + wc * 64 + nt * 16 + l15;
        const float bv = bias[colg];
#pragma unroll
        for (int mt = 0; mt < 4; ++mt) {
#pragma unroll
            for (int r = 0; r < 4; ++r) {
                const int rowg = m0 + wr * 64 + mt * 16 + kq * 4 + r;
                const float v = acc[mt][nt][r] + bv;
                if (OUT_BF16)
                    ((u16*)Cout)[(size_t)rowg * N + colg] = f2bf(v);
                else
                    ((float*)Cout)[(size_t)rowg * N + colg] = v;
            }
        }
    }
}

// ---------------------------------------------------------------------------
// RoPE cos/sin table: ct/st[t][d2], d2 in [0,64).
// ---------------------------------------------------------------------------
__global__ __launch_bounds__(256) void rope_table(
    float* __restrict__ ct, float* __restrict__ st)
{
    const int i = blockIdx.x * 256 + threadIdx.x;   // t*64 + d2
    const int d2 = i & 63, t = i >> 6;
    const float invf = expf(-(float)d2 * (9.210340371976184f / 64.0f));
    const float fr = (float)t * invf;
    ct[i] = cosf(fr);
    st[i] = sinf(fr);
}

// ---------------------------------------------------------------------------
// Fused RoPE + QKV relayout (single pass over qkv):
//   Qc[bh][t][d] = rope(q),  Kc[bh][t][d] = rope(k),  Vt[bh][d][t] = v.
// One thread per (b,h,t) row. 256 blocks x 256 threads.
// ---------------------------------------------------------------------------
__global__ __launch_bounds__(256) void rope_kv(
    const u16* __restrict__ qkv, const float* __restrict__ ct,
    const float* __restrict__ st,
    u16* __restrict__ Qc, u16* __restrict__ Kc, u16* __restrict__ Vt)
{
    const int tid = threadIdx.x;
    const int blk = blockIdx.x;          // b(4) x h(16) x ttile(4)
    const int tt = blk & 3;
    const int h  = (blk >> 2) & 15;
    const int b  = blk >> 6;
    const int t  = tt * 256 + tid;
    const int bh = b * 16 + h;

    const size_t src  = ((size_t)(b * T_SEQ + t)) * QKV_N + h * D_HEAD;
    const size_t dst  = ((size_t)(bh * T_SEQ + t)) * D_HEAD;
    const size_t vdst = ((size_t)bh * D_HEAD) * T_SEQ + t;
    const float* crow = ct + t * 64;
    const float* srow = st + t * 64;

    // q and k: rope pairs (d, d+64), 8 elements per chunk
#pragma unroll
    for (int part = 0; part < 2; ++part) {
        const u16* in  = qkv + src + part * C_DIM;
        u16* outp      = (part ? Kc : Qc) + dst;
#pragma unroll
        for (int c = 0; c < 8; ++c) {
            uint4 u1 = *(const uint4*)(in + c * 8);
            uint4 u2 = *(const uint4*)(in + 64 + c * 8);
            float f1[8], f2[8], o1[8], o2[8];
            unpack8(u1, f1); unpack8(u2, f2);
#pragma unroll
            for (int i = 0; i < 8; ++i) {
                const float cv = crow[c * 8 + i], sv = srow[c * 8 + i];
                o1[i] = f1[i] * cv - f2[i] * sv;
                o2[i] = f1[i] * sv + f2[i] * cv;
            }
            *(uint4*)(outp + c * 8)      = pack8(o1);
            *(uint4*)(outp + 64 + c * 8) = pack8(o2);
        }
    }

    // v: copy to transposed layout (element stores, coalesced in t across lanes)
#pragma unroll
    for (int c = 0; c < 16; ++c) {
        uint4 v = *(const uint4*)(qkv + src + 2 * C_DIM + c * 8);
        u16 e[8];
        e[0] = (u16)(v.x & 0xffff); e[1] = (u16)(v.x >> 16);
        e[2] = (u16)(v.y & 0xffff); e[3] = (u16)(v.y >> 16);
        e[4] = (u16)(v.z & 0xffff); e[5] = (u16)(v.z >> 16);
        e[6] = (u16)(v.w & 0xffff); e[7] = (u16)(v.w >> 16);
#pragma unroll
        for (int j = 0; j < 8; ++j)
            Vt[vdst + (size_t)(c * 8 + j) * T_SEQ] = e[j];
    }
}

// ---------------------------------------------------------------------------
// MFMA flash attention, load-balanced: block = (pair p, bh) handles q-tiles
// p and 15-p sequentially -> exactly 17 K-tile steps per block (uniform).
// 4 waves, wave w owns 16 q-rows of the current tile. QK^T and PV on matrix
// cores, fp32 online softmax in registers, P via per-wave LDS round-trip.
// ---------------------------------------------------------------------------
__global__ __launch_bounds__(256) void attn_mfma(
    const u16* __restrict__ Qc,    // [B*H, T, D] roped
    const u16* __restrict__ Kc,    // [B*H, T, D] roped
    const u16* __restrict__ Vt,    // [B*H, D, T]
    u16* __restrict__ y)           // [B, T, C]
{
    __shared__ alignas(16) char KsL[16384];     // [cd(16)][row(64)][16B]
    __shared__ alignas(16) char VtsL[16384];    // [jc(8)][drow(128)][16B]
    __shared__ alignas(16) char PwL[4][2176];   // per-wave [jc(8)][q(16)][16B]+pad

    const int tid  = threadIdx.x;
    const int lane = tid & 63;
    const int w    = tid >> 6;
    const int l15  = lane & 15;
    const int l4   = lane >> 4;
    const int p    = blockIdx.x;     // 0..7
    const int bh   = blockIdx.y;     // 0..63
    const int h    = bh & 15;
    const int b    = bh >> 4;

    const size_t kbase = (size_t)bh * T_SEQ * D_HEAD;
    const size_t vbase = (size_t)bh * D_HEAD * T_SEQ;
    const float scale = 0.08838834764831845f;   // 1/sqrt(128)
    char* pw = PwL[w];

    for (int half = 0; half < 2; ++half) {
        const int qt = half ? (15 - p) : p;

        // Q fragments (A-layout: m=lane&15, k=(lane>>4)*8+j)
        const int qrow = qt * 64 + w * 16 + l15;
        const u16* qptr = Qc + ((size_t)(bh * T_SEQ + qrow)) * D_HEAD;
        bf16x8 qf[4];
#pragma unroll
        for (int f = 0; f < 4; ++f)
            qf[f] = __builtin_bit_cast(bf16x8, *(const uint4*)(qptr + f * 32 + l4 * 8));

        f32x4 o[8] = {};                 // O[q=l4*4+r][d=db*16+l15]
        float mrow[4] = {-1e30f, -1e30f, -1e30f, -1e30f};
        float lrow[4] = {};

        for (int kt = 0; kt <= qt; ++kt) {
            __syncthreads();             // done reading prev Ks/Vts
            {
                const u16* ksrc = Kc + kbase + (size_t)(kt * 64 + lane) * D_HEAD;
#pragma unroll
                for (int i = 0; i < 4; ++i) {
                    const int cd = w * 4 + i;
                    __builtin_amdgcn_global_load_lds(AS1C(ksrc + cd * 8),
                                                     AS3(KsL + cd * 1024), 16, 0, 0);
                }
            }
#pragma unroll
            for (int i = 0; i < 4; ++i) {
                const int jc = w + (i >> 1) * 4;
                const int dh = i & 1;
                const u16* vsrc = Vt + vbase + (size_t)(dh * 64 + lane) * T_SEQ
                                  + kt * 64 + jc * 8;
                __builtin_amdgcn_global_load_lds(AS1C(vsrc),
                                                 AS3(VtsL + jc * 2048 + dh * 1024), 16, 0, 0);
            }
            __syncthreads();             // staging visible

            // scores: S[q][k] via 16 MFMAs
            f32x4 sacc[4] = {};
#pragma unroll
            for (int nb = 0; nb < 4; ++nb)
#pragma unroll
                for (int kc = 0; kc < 4; ++kc) {
                    bf16x8 kf = __builtin_bit_cast(bf16x8,
                        *(const uint4*)(KsL + (kc * 4 + l4) * 1024 + (nb * 16 + l15) * 16));
                    sacc[nb] = __builtin_amdgcn_mfma_f32_16x16x32_bf16(
                        qf[kc], kf, sacc[nb], 0, 0, 0);
                }

            // scale + causal mask (diagonal tile only)
#pragma unroll
            for (int nb = 0; nb < 4; ++nb)
#pragma unroll
                for (int r = 0; r < 4; ++r) {
                    float s = sacc[nb][r] * scale;
                    if (kt == qt && (nb * 16 + l15) > (w * 16 + l4 * 4 + r))
                        s = -1e30f;
                    sacc[nb][r] = s;
                }

            // online softmax per row
            float alpha[4];
#pragma unroll
            for (int r = 0; r < 4; ++r) {
                float mx = fmaxf(fmaxf(sacc[0][r], sacc[1][r]),
                                 fmaxf(sacc[2][r], sacc[3][r]));
#pragma unroll
                for (int off = 1; off < 16; off <<= 1)
                    mx = fmaxf(mx, __shfl_xor(mx, off, 64));
                const float mn = fmaxf(mrow[r], mx);
                alpha[r] = __expf(mrow[r] - mn);
                mrow[r] = mn;
                float ls = 0.f;
#pragma unroll
                for (int nb = 0; nb < 4; ++nb) {
                    const float e = __expf(sacc[nb][r] - mn);
                    sacc[nb][r] = e;
                    ls += e;
                }
#pragma unroll
                for (int off = 1; off < 16; off <<= 1)
                    ls += __shfl_xor(ls, off, 64);
                lrow[r] = lrow[r] * alpha[r] + ls;
            }

            // rescale O
#pragma unroll
            for (int db = 0; db < 8; ++db)
#pragma unroll
                for (int r = 0; r < 4; ++r)
                    o[db][r] *= alpha[r];

            // P: C-layout regs -> bf16 -> per-wave LDS in A-layout chunks
#pragma unroll
            for (int nb = 0; nb < 4; ++nb)
#pragma unroll
                for (int r = 0; r < 4; ++r) {
                    const int j = nb * 16 + l15;
                    const int q = l4 * 4 + r;
                    *(u16*)(pw + (j >> 3) * 272 + q * 16 + (j & 7) * 2) =
                        f2bf(sacc[nb][r]);
                }

            // PV: O += P @ V
            bf16x8 pf[2];
#pragma unroll
            for (int kc2 = 0; kc2 < 2; ++kc2)
                pf[kc2] = __builtin_bit_cast(bf16x8,
                    *(const uint4*)(pw + (kc2 * 4 + l4) * 272 + l15 * 16));
#pragma unroll
            for (int db = 0; db < 8; ++db)
#pragma unroll
                for (int kc2 = 0; kc2 < 2; ++kc2) {
                    bf16x8 vf = __builtin_bit_cast(bf16x8,
                        *(const uint4*)(VtsL + (kc2 * 4 + l4) * 2048 + (db * 16 + l15) * 16));
                    o[db] = __builtin_amdgcn_mfma_f32_16x16x32_bf16(
                        pf[kc2], vf, o[db], 0, 0, 0);
                }
        }

        // epilogue: normalize and write this q-tile
        float inv[4];
#pragma unroll
        for (int r = 0; r < 4; ++r) inv[r] = 1.f / lrow[r];
#pragma unroll
        for (int db = 0; db < 8; ++db)
#pragma unroll
            for (int r = 0; r < 4; ++r) {
                const int q = qt * 64 + w * 16 + l4 * 4 + r;
                const int d = h * D_HEAD + db * 16 + l15;
                y[(size_t)(b * T_SEQ + q) * C_DIM + d] = f2bf(o[db][r] * inv[r]);
            }
        __syncthreads();   // protect LDS before second half restages
    }
}

// ---------------------------------------------------------------------------
extern "C" void kernel_launch(void* const* d_in, const int* in_sizes, int n_in,
                              void* d_out, int out_size, void* d_ws, size_t ws_size,
                              hipStream_t stream) {
    const float* x      = (const float*)d_in[0];
    const float* w_attn = (const float*)d_in[1];
    const float* b_attn = (const float*)d_in[2];
    const float* w_proj = (const float*)d_in[3];
    const float* b_proj = (const float*)d_in[4];
    float* out = (float*)d_out;

    char* ws = (char*)d_ws;
    // Phase 1 (pre-GEMM1): xb, waT.  Phase 2 (post-GEMM1, region reuse):
    // Qc, Kc, Vt overwrite xb/waT; wpT overwrites consumed qkv; tables sit
    // in the not-yet-written yb region. High-water: 117.44 MB.
    u16* xb   = (u16*)(ws);                        // [4096][2048]    16.78 MB
    u16* waT  = (u16*)(ws + 16777216);             // [6144][2048]    25.17 MB
    u16* Qc   = (u16*)(ws);                        // [64][1024][128] 16.78 MB
    u16* Kc   = (u16*)(ws + 16777216);             // [64][1024][128] 16.78 MB
    u16* Vt   = (u16*)(ws + 33554432);             // [64][128][1024] 16.78 MB
    u16* qkvb = (u16*)(ws + 50331648);             // [4096][6144]    50.33 MB
    u16* wpT  = (u16*)(ws + 50331648);             // [2048][2048]     8.39 MB (after rope_kv)
    u16* yb   = (u16*)(ws + 100663296);            // [4096][2048]    16.78 MB
    float* ct = (float*)(ws + 100663296);          // [1024][64] 256 KB (dead before attn)
    float* st = ct + 65536;

    // 1) input cast + w_attn transpose + rope table
    cast_bf16<<<(BT * C_DIM / 4) / 256, 256, 0, stream>>>(x, xb);
    transpose_cast<<<dim3(QKV_N / 32, C_DIM / 32), 256, 0, stream>>>(w_attn, waT, C_DIM, QKV_N);
    rope_table<<<(T_SEQ * 64) / 256, 256, 0, stream>>>(ct, st);

    // 2) qkv = x @ w_attn + b_attn  (bf16 out)
    gemm_bf16_mfma<1><<<dim3(QKV_N / 128, BT / 128), 256, 0, stream>>>(
        xb, waT, b_attn, qkvb, BT, QKV_N, C_DIM);

    // 3) fused RoPE + relayout -> Qc, Kc, Vt (consumes qkvb and tables)
    rope_kv<<<256, 256, 0, stream>>>(qkvb, ct, st, Qc, Kc, Vt);

    // 4) w_proj transpose into the now-dead qkv region
    transpose_cast<<<dim3(C_DIM / 32, C_DIM / 32), 256, 0, stream>>>(w_proj, wpT, C_DIM, C_DIM);

    // 5) load-balanced MFMA flash attention -> yb [B,T,C] bf16
    attn_mfma<<<dim3(8, 4 * H_NUM), 256, 0, stream>>>(Qc, Kc, Vt, yb);

    // 6) out = y @ w_proj + b_proj  (fp32 out)
    gemm_bf16_mfma<0><<<dim3(C_DIM / 128, BT / 128), 256, 0, stream>>>(
        yb, wpT, b_proj, out, BT, C_DIM, C_DIM);
}